// Round 10
// baseline (173.517 us; speedup 1.0000x reference)
//
#include <hip/hip_runtime.h>
#include <math.h>

#pragma clang fp contract(off)

#define NIMG 16
#define NP   8732
#define NCLS 81
#define NFG  80
#define KTOP 1000
#define KPAD 1024
#define DETS 100
#define CAPMAX 166912          // >= 19*8732 (hard bound: <=19 softmax scores can exceed 0.05)
#define BASEBITS 0x3D000000u   // float bits of 0.03125, below 0.05 threshold; low 21 bits zero
#define CNT_STRIDE 64          // u32 units -> 256 B per image counter (own cacheline)
#define TILEB 137              // 64-prior tiles per image (137*64 >= 8732)

// ---- workspace layout (bytes) ----
#define OFF_BOXES  0u            // [NIMG][NP][4] f32 = 2,235,392
#define OFF_CNT    2235392u      // [NIMG] u32 @256B = 4,096
#define OFF_CSCORE 2239488u      // [NIMG][KPAD] f32
#define OFF_CLABEL 2305024u      // [NIMG][KPAD] i32
#define OFF_CBOX   2370560u      // [NIMG][KPAD] float4
#define OFF_COFFS  2632704u      // [NIMG][KPAD] float4
#define OFF_CAREA  2894848u      // [NIMG][KPAD] f32
#define OFF_VALIDW 2960384u      // [NIMG][16] u64
#define OFF_MASK   2962432u      // [NIMG][16][KPAD] u64 column-major
#define OFF_CAND   5059584u      // [NIMG][cap] u64

typedef unsigned long long u64;
typedef unsigned int u32;

#define AS_GLOBAL __attribute__((address_space(1)))
#define AS_LOCAL  __attribute__((address_space(3)))

// ============================================================ kernel 1
// 4 waves per 64-prior tile; quarter q of prior handles classes c==q mod 4
// (bit-identical partial max/sum combine). Verified R7/R8/R9.
__global__ __launch_bounds__(256, 6) void k_decode(
    const float* __restrict__ logits, const float* __restrict__ rel,
    const float* __restrict__ priors, const int* __restrict__ tsz,
    float* __restrict__ boxes_out, u64* __restrict__ cand,
    u32* __restrict__ cnt, int cap)
{
#pragma clang fp contract(off)
    __shared__ __align__(16) float lx[64 * NCLS];   // 20,736 B flat [prior][class]
    __shared__ float pmx[4 * 64];
    __shared__ float psm[4 * 64];
    __shared__ u32 sok[64];
    __shared__ u32 wtt[4];
    __shared__ u32 sbase;
    int b  = blockIdx.x / TILEB;
    int g  = blockIdx.x - b * TILEB;
    int p0 = g * 64;
    int t  = threadIdx.x;
    int lane = t & 63;
    int q = t >> 6;
    int npri = NP - p0; if (npri > 64) npri = 64;
    int words = npri * NCLS;

    // ---- async staging: chunks split across the 4 waves, one barrier ----
    const u32* s32 = (const u32*)(logits + ((size_t)b * NP + p0) * NCLS);
    u32* lxw = (u32*)lx;
    int full = words >> 8;                          // 1KB chunks (64 x 16 B)
    for (int k = q; k < full; k += 4)
        __builtin_amdgcn_global_load_lds(
            (AS_GLOBAL const u32*)(s32 + (k << 8) + (lane << 2)),
            (AS_LOCAL u32*)(lxw + (k << 8)), 16, 0, 0);
    int base = full << 8;
    int c4 = (words - base) >> 6;                   // 256B chunks (64 x 4 B)
    for (int k = q; k < c4; k += 4)
        __builtin_amdgcn_global_load_lds(
            (AS_GLOBAL const u32*)(s32 + base + (k << 6) + lane),
            (AS_LOCAL u32*)(lxw + base + (k << 6)), 4, 0, 0);
    int base2 = base + (c4 << 6);
    if (q == 0 && lane < words - base2) lxw[base2 + lane] = s32[base2 + lane];

    int p = p0 + lane;
    bool active = p < NP;

    // ---- box decode by wave 0 (independent of LDS; overlaps DMA) ----
    if (q == 0) {
        u32 ok = 0;
        if (active) {
            float4 pr = ((const float4*)priors)[p];
            float4 rl = ((const float4*)rel)[(size_t)b * NP + p];
            float W = (float)tsz[b * 2 + 1], H = (float)tsz[b * 2 + 0];
            float cx = pr.x + (rl.x * 0.1f) * pr.z;
            float cy = pr.y + (rl.y * 0.1f) * pr.w;
            float w_ = pr.z * expf(rl.z * 0.2f);
            float h_ = pr.w * expf(rl.w * 0.2f);
            float4 bx;
            bx.x = (cx - 0.5f * w_) * W; bx.y = (cy - 0.5f * h_) * H;
            bx.z = (cx + 0.5f * w_) * W; bx.w = (cy + 0.5f * h_) * H;
            ((float4*)boxes_out)[(size_t)b * NP + p] = bx;
            ok = ((bx.z - bx.x) >= 0.01f) && ((bx.w - bx.y) >= 0.01f);
        }
        sok[lane] = ok;
    }
    __syncthreads();                                 // #1: DMA drained + sok

    int tb = lane * NCLS;
    int nk = (q == 0) ? 21 : 20;                     // q==0 also owns c=80
    float x[21];
    #pragma unroll
    for (int k = 0; k < 21; ++k) {
        int c = q + 4 * k;
        x[k] = (k < nk) ? lx[tb + c] : -3.4e38f;
    }
    float pm = -3.4e38f;
    #pragma unroll
    for (int k = 0; k < 21; ++k) if (k < nk) pm = fmaxf(pm, x[k]);
    pmx[q * 64 + lane] = pm;
    __syncthreads();                                 // #2: partial max
    float m = fmaxf(fmaxf(pmx[lane], pmx[64 + lane]),
                    fmaxf(pmx[128 + lane], pmx[192 + lane]));

    float ps = 0.f;
    #pragma unroll
    for (int k = 0; k < 21; ++k) {
        if (k < nk) { x[k] = expf(x[k] - m); ps += x[k]; }
    }
    psm[q * 64 + lane] = ps;
    __syncthreads();                                 // #3: partial sum
    float s = (psm[lane] + psm[64 + lane]) + (psm[128 + lane] + psm[192 + lane]);

    float hi = 0.05000075f * s;
    float lo = 0.04999925f * s;
    u32 pass = 0, band = 0;
    u32 sizeok = sok[lane];
    if (active && sizeok) {
        #pragma unroll
        for (int k = 0; k < 21; ++k) {
            int c = q + 4 * k;
            if (k < nk && c >= 1) {
                bool pa = x[k] > hi;
                bool bd = (!pa) && (x[k] > lo);
                pass |= ((u32)pa) << k;
                band |= ((u32)bd) << k;
            }
        }
    }
    while (band) {
        int k = __builtin_ctz(band); band &= band - 1;
        int c = q + 4 * k;
        float e = expf(lx[tb + c] - m);
        if (e / s > 0.05f) pass |= 1u << k;
    }
    int cnt_t = __popc(pass);

    int pre = cnt_t;
    #pragma unroll
    for (int d = 1; d < 64; d <<= 1) {
        int o = __shfl_up(pre, d);
        if (lane >= d) pre += o;
    }
    if (lane == 63) wtt[q] = (u32)pre;
    __syncthreads();                                 // #4: wave totals
    u32 before = 0;
    for (int w = 0; w < 4; ++w) if (w < q) before += wtt[w];
    if (t == 0) {
        u32 tot = wtt[0] + wtt[1] + wtt[2] + wtt[3];
        sbase = tot ? atomicAdd(cnt + b * CNT_STRIDE, tot) : 0u;
    }
    __syncthreads();                                 // #5: block base
    u32 pos = sbase + before + (u32)(pre - cnt_t);

    u64* cb = cand + (size_t)b * cap;
    u32 flatneg = 0xFFFFFFFFu - (u32)p * NFG;
    while (pass) {
        int k = __builtin_ctz(pass); pass &= pass - 1;
        int c = q + 4 * k;
        float e = expf(lx[tb + c] - m);
        float d = e / s;
        if ((int)pos < cap)
            cb[pos] = ((u64)__float_as_uint(d) << 32) | (u64)(flatneg - (u32)(c - 1));
        ++pos;
    }
}

// ============================================================ suffix_find
// (rare fine-fallback path only): 8192-bin hierarchical suffix scan.
__device__ __forceinline__ void suffix_find(
    u32* hist, u32* wt, u32 K, int tid,
    volatile int* outI, volatile u32* outNext)
{
    int lane = tid & 63, w = tid >> 6;
    u32 v[8]; u32 tot = 0;
    #pragma unroll
    for (int k = 0; k < 8; ++k) { v[k] = hist[tid * 8 + k]; tot += v[k]; }
    u32 ws = tot;
    #pragma unroll
    for (int d = 1; d < 64; d <<= 1) {
        u32 o = __shfl_down(ws, d);
        if (lane + d < 64) ws += o;
    }
    if (lane == 0) wt[w] = ws;
    __syncthreads();
    u32 tail = 0;
    for (int w2 = w + 1; w2 < 16; ++w2) tail += wt[w2];
    u32 after = (ws - tot) + tail;
    u32 sufk[9];
    sufk[8] = after;
    #pragma unroll
    for (int k = 7; k >= 0; --k) sufk[k] = v[k] + sufk[k + 1];
    #pragma unroll
    for (int k = 0; k < 8; ++k) {
        if (sufk[k] >= K && sufk[k + 1] < K) {
            *outI = tid * 8 + k;
            *outNext = sufk[k + 1];
        }
    }
    __syncthreads();
}

// ============================================================ kernel 2
// FUSED select. R9 lesson: hot-bin same-address LDS atomics serialized the
// flat 1280-bin hist (scores cluster just above 0.05). Fix: two-level 64-bin
// hist with 32-way column replication h[bin*32+(t&31)] -> bank==lane&31
// (conflict-free), <=2 lanes/address per access. T value bit-identical:
// BASEBITS + (c1<<21) + (c2<<15) == BASEBITS + ((64*c1+c2)<<15).
__global__ __launch_bounds__(1024) void k_select(
    const u64* __restrict__ cand, const u32* __restrict__ cnt,
    const float* __restrict__ boxes,
    float* __restrict__ cscore, int* __restrict__ clabel,
    float4* __restrict__ cbox, float4* __restrict__ coffs,
    float* __restrict__ carea, u64* __restrict__ validw, int cap)
{
#pragma clang fp contract(off)
    __shared__ u32 h1[64 * 32];     // level-1: (sb-BASE)>>21, 32 columns (8 KB)
    __shared__ u32 h2[64 * 32];     // level-2: (sb>>15)&63 within c1 (8 KB)
    __shared__ u32 fh[8192];        // rare fine fallback
    __shared__ u32 wt[16];
    __shared__ u64 buf[2048];
    __shared__ float red16[16];
    __shared__ int sh_c1, sh_c2, sh_i2;
    __shared__ u32 sh_n1hi, sh_S, sh_n2hi, sh_d, sh_m;
    int b = blockIdx.x, t = threadIdx.x, lane = t & 63, col = t & 31;
    u32 n = min(cnt[b * CNT_STRIDE], (u32)cap);
    const u64* cb = cand + (size_t)b * cap;

    for (int i = t; i < 64 * 32; i += 1024) { h1[i] = 0; h2[i] = 0; }
    if (t == 0) { sh_c1 = -2; sh_c2 = -2; sh_i2 = -2;
                  sh_n1hi = 0; sh_S = 0; sh_n2hi = 0; sh_m = 0; }
    __syncthreads();

    // ---- phase A: level-1 hist over all keys (8 keys/thread-iter) ----
    if (t == 0 && (n & 1)) {
        u32 sb = (u32)(cb[n - 1] >> 32);
        u32 bb = (sb - BASEBITS) >> 21; if (bb > 63u) bb = 63u;
        atomicAdd(&h1[bb * 32], 1u);
    }
    u32 npair = n >> 1;
    for (u32 bs0 = 0; bs0 < npair; bs0 += 4096) {
        u32 i0 = bs0 + (u32)t;
        uint4 va, vb, vc, vd;
        bool q0 = i0 < npair, q1 = i0 + 1024 < npair,
             q2 = i0 + 2048 < npair, q3 = i0 + 3072 < npair;
        if (q0) va = ((const uint4*)cb)[i0];
        if (q1) vb = ((const uint4*)cb)[i0 + 1024];
        if (q2) vc = ((const uint4*)cb)[i0 + 2048];
        if (q3) vd = ((const uint4*)cb)[i0 + 3072];
        u32 sbv[8]; int nv = 0;
        if (q0) { sbv[nv++] = va.y; sbv[nv++] = va.w; }
        if (q1) { sbv[nv++] = vb.y; sbv[nv++] = vb.w; }
        if (q2) { sbv[nv++] = vc.y; sbv[nv++] = vc.w; }
        if (q3) { sbv[nv++] = vd.y; sbv[nv++] = vd.w; }
        for (int e = 0; e < nv; ++e) {
            u32 bb = (sbv[e] - BASEBITS) >> 21; if (bb > 63u) bb = 63u;
            atomicAdd(&h1[bb * 32 + col], 1u);
        }
    }
    __syncthreads();
    // ---- wave-0: reduce columns + suffix; boundary c1 ----
    if (t < 64) {
        u32 v = 0;
        #pragma unroll
        for (int k = 0; k < 32; ++k) v += h1[t * 32 + ((k + t) & 31)];
        u32 ws = v;
        #pragma unroll
        for (int d = 1; d < 64; d <<= 1) {
            u32 o = (u32)__shfl_down((int)ws, d);
            if (t + d < 64) ws += o;
        }
        if (ws >= (u32)KTOP && (ws - v) < (u32)KTOP) { sh_c1 = t; sh_n1hi = ws - v; }
    }
    __syncthreads();
    int c1 = sh_c1;
    u32 T = 0;
    if (c1 >= 0) {
        u32 n1hi = sh_n1hi;
        // ---- phase B: level-2 hist over keys in bin c1 ----
        if (t == 0 && (n & 1)) {
            u32 sb = (u32)(cb[n - 1] >> 32);
            u32 bb = (sb - BASEBITS) >> 21; if (bb > 63u) bb = 63u;
            if ((int)bb == c1) atomicAdd(&h2[((sb >> 15) & 63u) * 32], 1u);
        }
        for (u32 bs0 = 0; bs0 < npair; bs0 += 4096) {
            u32 i0 = bs0 + (u32)t;
            uint4 va, vb, vc, vd;
            bool q0 = i0 < npair, q1 = i0 + 1024 < npair,
                 q2 = i0 + 2048 < npair, q3 = i0 + 3072 < npair;
            if (q0) va = ((const uint4*)cb)[i0];
            if (q1) vb = ((const uint4*)cb)[i0 + 1024];
            if (q2) vc = ((const uint4*)cb)[i0 + 2048];
            if (q3) vd = ((const uint4*)cb)[i0 + 3072];
            u32 sbv[8]; int nv = 0;
            if (q0) { sbv[nv++] = va.y; sbv[nv++] = va.w; }
            if (q1) { sbv[nv++] = vb.y; sbv[nv++] = vb.w; }
            if (q2) { sbv[nv++] = vc.y; sbv[nv++] = vc.w; }
            if (q3) { sbv[nv++] = vd.y; sbv[nv++] = vd.w; }
            for (int e = 0; e < nv; ++e) {
                u32 bb = (sbv[e] - BASEBITS) >> 21; if (bb > 63u) bb = 63u;
                if ((int)bb == c1)
                    atomicAdd(&h2[((sbv[e] >> 15) & 63u) * 32 + col], 1u);
            }
        }
        __syncthreads();
        if (t < 64) {
            u32 v = 0;
            #pragma unroll
            for (int k = 0; k < 32; ++k) v += h2[t * 32 + ((k + t) & 31)];
            u32 ws = v;
            #pragma unroll
            for (int d = 1; d < 64; d <<= 1) {
                u32 o = (u32)__shfl_down((int)ws, d);
                if (t + d < 64) ws += o;
            }
            u32 K2 = (u32)KTOP - n1hi;
            if (ws >= K2 && (ws - v) < K2) {
                sh_c2 = t; sh_S = n1hi + ws; sh_n2hi = n1hi + (ws - v);
            }
        }
        __syncthreads();
        int c2 = sh_c2;                              // exists: suffix(c1) >= K2
        u32 Tc = BASEBITS + ((u32)c1 << 21) + ((u32)c2 << 15);
        if (sh_S <= 2048u) {
            T = Tc;                                  // common path (bit-identical)
        } else {                                     // rare: granularity-4 refine
            u32 nhi = sh_n2hi;
            for (int i = t; i < 8192; i += 1024) fh[i] = 0;
            __syncthreads();
            for (u32 i = (u32)t; i < n; i += 1024) {
                u32 sb = (u32)(cb[i] >> 32);
                if ((sb & 0xFFFF8000u) == Tc)
                    atomicAdd(&fh[(sb >> 2) & 0x1FFFu], 1u);
            }
            __syncthreads();
            suffix_find(fh, wt, (u32)KTOP - nhi, t, &sh_i2, &sh_d);
            T = (sh_i2 >= 0) ? (Tc + ((u32)sh_i2 << 2)) : Tc;
        }
    }
    // ---- compact survivors (>= T) into LDS buf, 4 keys/thread-iter ----
    for (u32 bs0 = 0; bs0 < n; bs0 += 4096) {
        u32 i0 = bs0 + (u32)t;
        u64 k0 = 0, k1 = 0, k2 = 0, k3 = 0;
        bool q0 = i0 < n, q1 = i0 + 1024 < n, q2 = i0 + 2048 < n, q3 = i0 + 3072 < n;
        if (q0) k0 = cb[i0];
        if (q1) k1 = cb[i0 + 1024];
        if (q2) k2 = cb[i0 + 2048];
        if (q3) k3 = cb[i0 + 3072];
        #pragma unroll
        for (int e = 0; e < 4; ++e) {
            u64 key = (e == 0) ? k0 : (e == 1) ? k1 : (e == 2) ? k2 : k3;
            bool pr = (e == 0) ? q0 : (e == 1) ? q1 : (e == 2) ? q2 : q3;
            bool pick = pr && ((u32)(key >> 32) >= T);
            u64 bal = __ballot(pick);
            u32 wb = 0;
            if (lane == 0 && bal) wb = atomicAdd(&sh_m, (u32)__popcll(bal));
            wb = (u32)__shfl((int)wb, 0);
            if (pick) {
                u32 pos = wb + (u32)__popcll(bal & ((1ULL << lane) - 1ULL));
                if (pos < 2048) buf[pos] = key;
            }
        }
    }
    __syncthreads();
    u32 m = min(sh_m, 2048u);
    for (int i = t; i < 2048; i += 1024) if ((u32)i >= m) buf[i] = 0ULL;
    __syncthreads();
    // ---- hybrid bitonic sort, 2048 elems, full-key desc ----
    for (int k = 2; k <= 2048; k <<= 1) {
        for (int j = k >> 1; j >= 64; j >>= 1) {
            #pragma unroll
            for (int e = 0; e < 2; ++e) {
                int i = t + e * 1024;
                int ixj = i ^ j;
                if (ixj > i) {
                    u64 a = buf[i], bb = buf[ixj];
                    bool up = (i & k) == 0;
                    if (up ? (a < bb) : (a > bb)) { buf[i] = bb; buf[ixj] = a; }
                }
            }
            __syncthreads();
        }
        u64 v0 = buf[t], v1 = buf[t + 1024];
        bool up0 = (t & k) == 0;
        bool up1 = ((t + 1024) & k) == 0;
        int js = ((k >> 1) < 32) ? (k >> 1) : 32;
        for (int j = js; j >= 1; j >>= 1) {
            u64 o0 = __shfl_xor(v0, j);
            u64 o1 = __shfl_xor(v1, j);
            bool lo0 = (t & j) == 0;
            v0 = (lo0 == up0) ? (v0 > o0 ? v0 : o0) : (v0 < o0 ? v0 : o0);
            v1 = (lo0 == up1) ? (v1 > o1 ? v1 : o1) : (v1 < o1 ? v1 : o1);
        }
        buf[t] = v0; buf[t + 1024] = v1;
        __syncthreads();
    }
    // ---- fused prep: t owns slot t of KPAD ----
    u64 key = (t < KTOP) ? buf[t] : 0ULL;
    float s = __uint_as_float((u32)(key >> 32));
    bool valid = s > 0.0f;
    u32 flat = valid ? (0xFFFFFFFFu - (u32)key) : 0u;
    int prior = (int)(flat / NFG);
    int cls = (int)(flat - (u32)prior * NFG) + 1;
    float4 bx = make_float4(0.f, 0.f, 0.f, 0.f);
    if (valid) bx = ((const float4*)boxes)[b * NP + prior];
    cscore[b * KPAD + t] = s;
    clabel[b * KPAD + t] = cls;
    cbox[b * KPAD + t] = bx;
    u64 vb = __ballot(valid);
    if (lane == 0) validw[b * 16 + (t >> 6)] = vb;
    float lm = valid ? fmaxf(fmaxf(bx.x, bx.y), fmaxf(bx.z, bx.w)) : 0.0f;
    lm = fmaxf(lm, 0.0f);
    #pragma unroll
    for (int d = 1; d < 64; d <<= 1) lm = fmaxf(lm, __shfl_xor(lm, d));
    if (lane == 0) red16[t >> 6] = lm;
    __syncthreads();
    float mc = red16[0];
    #pragma unroll
    for (int w = 1; w < 16; ++w) mc = fmaxf(mc, red16[w]);
    float off = (float)cls * (mc + 1.0f);
    float4 ob = valid ? make_float4(bx.x + off, bx.y + off, bx.z + off, bx.w + off)
                      : make_float4(0.f, 0.f, 0.f, 0.f);
    float area = valid ? (ob.z - ob.x) * (ob.w - ob.y) : 0.0f;
    coffs[b * KPAD + t] = ob;
    carea[b * KPAD + t] = area;
}

// ============================================================ kernel 3
// suppression bitmask, COLUMN-major: cmask[b][w][j] bit k = row (64w+k)
// suppresses column j. 256 blocks (keeps iou work spread across CUs).
__global__ __launch_bounds__(1024) void k_iou(
    const float4* __restrict__ coffs, const float* __restrict__ carea,
    u64* __restrict__ cmask)
{
#pragma clang fp contract(off)
    __shared__ float4 bs[KPAD];
    __shared__ float as_[KPAD];
    int b = blockIdx.x >> 4, tile = blockIdx.x & 15;
    int t = threadIdx.x;
    bs[t] = coffs[b * KPAD + t];
    as_[t] = carea[b * KPAD + t];
    __syncthreads();
    int j = tile * 64 + (t & 63);                  // column (suppressee)
    int w = t >> 6;                                // row word
    float4 bj = bs[j];
    float aj = as_[j];
    int r0 = w * 64;
    u64 bits = 0;
    #pragma unroll 4
    for (int k = 0; k < 64; ++k) {
        int r = r0 + k;                            // wave-uniform row
        float4 br = bs[r];
        float ar = as_[r];
        float ltx = fmaxf(br.x, bj.x), lty = fmaxf(br.y, bj.y);
        float rbx = fminf(br.z, bj.z), rby = fminf(br.w, bj.w);
        float wx = fmaxf(rbx - ltx, 0.0f), wy = fmaxf(rby - lty, 0.0f);
        float inter = wx * wy;
        float denom = ((ar + aj) - inter) + 1e-9f;
        float iou = inter / denom;
        bool sup = (iou > 0.45f) && (j > r);
        bits |= ((u64)sup) << k;
    }
    cmask[((size_t)b * 16 + w) * KPAD + j] = bits;
}

// ============================================================ kernel 4
// NMS via ballot fixpoint (greedy kept-set = unique fixpoint; typ. <5 iters).
__global__ __launch_bounds__(64) void k_nms(
    const u64* __restrict__ cmask, const u64* __restrict__ validw,
    const float* __restrict__ cscore, const int* __restrict__ clabel,
    const float4* __restrict__ cbox, float* __restrict__ out)
{
    int b = blockIdx.x, lane = threadIdx.x;
    const u64* cm = cmask + (size_t)b * 16 * KPAD;
    u64 kept[16];
    u64 cw[16];
    #pragma unroll
    for (int w = 0; w < 16; ++w) cw[w] = cm[w * KPAD + lane];   // group 0 cols
    #pragma unroll
    for (int g = 0; g < 16; ++g) {
        u64 vg = validw[b * 16 + g];
        bool rem = false;
        #pragma unroll
        for (int w = 0; w < 16; ++w)
            if (w < g) rem |= (kept[w] & cw[w]) != 0ULL;
        u64 cg = cw[g];
        bool myv = ((vg >> lane) & 1ULL) && !rem;
        if (g < 15) {                               // prefetch next group's cols
            int cbase = (g + 1) * 64 + lane;
            #pragma unroll
            for (int w = 0; w < 16; ++w) cw[w] = cm[w * KPAD + cbase];
        }
        u64 K = __ballot(myv);
        for (;;) {
            u64 K2 = __ballot(myv && ((K & cg) == 0ULL));
            if (K2 == K) break;
            K = K2;
        }
        kept[g] = K;                                // wave-uniform
    }
    __shared__ u64 sk[16];
    __shared__ int pfx[17];
    __shared__ int slot[DETS];
    if (lane == 0) {
        #pragma unroll
        for (int w = 0; w < 16; ++w) sk[w] = kept[w];
        int run = 0;
        #pragma unroll
        for (int l = 0; l < 16; ++l) { pfx[l] = run; run += __popcll(kept[l]); }
        pfx[16] = run;
    }
    __syncthreads();
    if (lane < 16) {
        int r = pfx[lane];
        u64 wv = sk[lane];
        while (wv && r < DETS) {
            int bit = __builtin_ctzll(wv);
            slot[r] = lane * 64 + bit;
            ++r;
            wv &= wv - 1;
        }
    }
    __syncthreads();
    int total = min(pfx[16], DETS);
    for (int r = lane; r < DETS; r += 64) {
        float4 bx = make_float4(0.f, 0.f, 0.f, 0.f);
        float s = 0.0f;
        int lb = -1;
        if (r < total) {
            int cdx = slot[r];
            bx = cbox[b * KPAD + cdx];
            s = cscore[b * KPAD + cdx];
            lb = clabel[b * KPAD + cdx];
        }
        float* ob = out + ((size_t)b * DETS + r) * 4;
        ob[0] = bx.x; ob[1] = bx.y; ob[2] = bx.z; ob[3] = bx.w;
        out[NIMG * DETS * 4 + b * DETS + r] = s;
        out[NIMG * DETS * 4 + NIMG * DETS + b * DETS + r] = (float)lb;
    }
}

// ============================================================ launch
extern "C" void kernel_launch(void* const* d_in, const int* in_sizes, int n_in,
                              void* d_out, int out_size, void* d_ws, size_t ws_size,
                              hipStream_t stream) {
    const float* logits = (const float*)d_in[0];
    const float* rel    = (const float*)d_in[1];
    const float* priors = (const float*)d_in[2];
    const int*   tsz    = (const int*)d_in[3];
    float* out = (float*)d_out;
    char* ws = (char*)d_ws;

    float* boxes  = (float*)(ws + OFF_BOXES);
    u32*   cnt    = (u32*)(ws + OFF_CNT);
    float* cscore = (float*)(ws + OFF_CSCORE);
    int*   clabel = (int*)(ws + OFF_CLABEL);
    float4* cbox  = (float4*)(ws + OFF_CBOX);
    float4* coffs = (float4*)(ws + OFF_COFFS);
    float* carea  = (float*)(ws + OFF_CAREA);
    u64*   validw = (u64*)(ws + OFF_VALIDW);
    u64*   cmask  = (u64*)(ws + OFF_MASK);
    u64*   cand   = (u64*)(ws + OFF_CAND);

    long long avail = ((long long)ws_size - (long long)OFF_CAND) / (NIMG * 8);
    int cap = (int)(avail < CAPMAX ? (avail > 0 ? avail : 1) : CAPMAX);
    cap &= ~1;                                    // even -> 16B-aligned per-image base

    hipMemsetAsync(cnt, 0, NIMG * CNT_STRIDE * 4, stream);
    k_decode<<<NIMG * TILEB, 256, 0, stream>>>(logits, rel, priors, tsz,
                                               boxes, cand, cnt, cap);
    k_select<<<NIMG, 1024, 0, stream>>>(cand, cnt, boxes, cscore, clabel,
                                        cbox, coffs, carea, validw, cap);
    k_iou<<<NIMG * 16, 1024, 0, stream>>>(coffs, carea, cmask);
    k_nms<<<NIMG, 64, 0, stream>>>(cmask, validw, cscore, clabel, cbox, out);
}

// Round 11
// 157.068 us; speedup vs baseline: 1.1047x; 1.1047x over previous
//
#include <hip/hip_runtime.h>
#include <math.h>

#pragma clang fp contract(off)

#define NIMG 16
#define NP   8732
#define NCLS 81
#define NFG  80
#define KTOP 1000
#define KPAD 1024
#define DETS 100
#define CAPMAX 166912          // >= 19*8732 (hard bound: <=19 softmax scores can exceed 0.05)
#define BASEBITS 0x3D000000u   // float bits of 0.03125, below 0.05 threshold; low 16 bits zero
#define CNT_STRIDE 64          // u32 units -> 256 B per image counter (own cacheline)
#define TILEB 137              // 64-prior tiles per image (137*64 >= 8732)
#define NB 640                 // hist bins: (sb-BASEBITS)>>16, clamp 639 (score<=1.0)

// ---- workspace layout (bytes) ----
#define OFF_BOXES  0u            // [NIMG][NP][4] f32 = 2,235,392
#define OFF_CNT    2235392u      // [NIMG] u32 @256B = 4,096
#define OFF_GHIST  2239488u      // [NIMG][640] u32 = 40,960
#define OFF_CSCORE 2280448u      // [NIMG][KPAD] f32
#define OFF_CLABEL 2345984u      // [NIMG][KPAD] i32
#define OFF_CBOX   2411520u      // [NIMG][KPAD] float4
#define OFF_COFFS  2673664u      // [NIMG][KPAD] float4
#define OFF_CAREA  2935808u      // [NIMG][KPAD] f32
#define OFF_VALIDW 3001344u      // [NIMG][16] u64
#define OFF_MASK   3003392u      // [NIMG][16][KPAD] u64 column-major
#define OFF_CAND   5100544u      // [NIMG][cap] u64
#define MEMSET_LEN 45056u        // cnt + ghist (contiguous)

typedef unsigned long long u64;
typedef unsigned int u32;

#define AS_GLOBAL __attribute__((address_space(1)))
#define AS_LOCAL  __attribute__((address_space(3)))

// ============================================================ kernel 1
// 4 waves per 64-prior tile (verified R7-R10). NEW (R11): per-block LDS
// 640-bin score hist, merged to global AFTER the emission loop (~14 nonzero
// bins/block). This is NOT R6's failure (500K inline chained global atomics):
// aggregated adds, ~30K total over 20K addresses across the whole kernel.
__global__ __launch_bounds__(256, 6) void k_decode(
    const float* __restrict__ logits, const float* __restrict__ rel,
    const float* __restrict__ priors, const int* __restrict__ tsz,
    float* __restrict__ boxes_out, u64* __restrict__ cand,
    u32* __restrict__ cnt, u32* __restrict__ ghist, int cap)
{
#pragma clang fp contract(off)
    __shared__ __align__(16) float lx[64 * NCLS];   // 20,736 B flat [prior][class]
    __shared__ float pmx[4 * 64];
    __shared__ float psm[4 * 64];
    __shared__ u32 sok[64];
    __shared__ u32 wtt[4];
    __shared__ u32 sbase;
    __shared__ u32 lhist[NB];                        // 2,560 B
    int b  = blockIdx.x / TILEB;
    int g  = blockIdx.x - b * TILEB;
    int p0 = g * 64;
    int t  = threadIdx.x;
    int lane = t & 63;
    int q = t >> 6;
    int npri = NP - p0; if (npri > 64) npri = 64;
    int words = npri * NCLS;

    // ---- async staging: chunks split across the 4 waves, one barrier ----
    const u32* s32 = (const u32*)(logits + ((size_t)b * NP + p0) * NCLS);
    u32* lxw = (u32*)lx;
    int full = words >> 8;                          // 1KB chunks (64 x 16 B)
    for (int k = q; k < full; k += 4)
        __builtin_amdgcn_global_load_lds(
            (AS_GLOBAL const u32*)(s32 + (k << 8) + (lane << 2)),
            (AS_LOCAL u32*)(lxw + (k << 8)), 16, 0, 0);
    int base = full << 8;
    int c4 = (words - base) >> 6;                   // 256B chunks (64 x 4 B)
    for (int k = q; k < c4; k += 4)
        __builtin_amdgcn_global_load_lds(
            (AS_GLOBAL const u32*)(s32 + base + (k << 6) + lane),
            (AS_LOCAL u32*)(lxw + base + (k << 6)), 4, 0, 0);
    int base2 = base + (c4 << 6);
    if (q == 0 && lane < words - base2) lxw[base2 + lane] = s32[base2 + lane];

    for (int i = t; i < NB; i += 256) lhist[i] = 0;  // overlaps DMA

    int p = p0 + lane;
    bool active = p < NP;

    // ---- box decode by wave 0 (independent of LDS; overlaps DMA) ----
    if (q == 0) {
        u32 ok = 0;
        if (active) {
            float4 pr = ((const float4*)priors)[p];
            float4 rl = ((const float4*)rel)[(size_t)b * NP + p];
            float W = (float)tsz[b * 2 + 1], H = (float)tsz[b * 2 + 0];
            float cx = pr.x + (rl.x * 0.1f) * pr.z;
            float cy = pr.y + (rl.y * 0.1f) * pr.w;
            float w_ = pr.z * expf(rl.z * 0.2f);
            float h_ = pr.w * expf(rl.w * 0.2f);
            float4 bx;
            bx.x = (cx - 0.5f * w_) * W; bx.y = (cy - 0.5f * h_) * H;
            bx.z = (cx + 0.5f * w_) * W; bx.w = (cy + 0.5f * h_) * H;
            ((float4*)boxes_out)[(size_t)b * NP + p] = bx;
            ok = ((bx.z - bx.x) >= 0.01f) && ((bx.w - bx.y) >= 0.01f);
        }
        sok[lane] = ok;
    }
    __syncthreads();                                 // #1: DMA drained + sok

    int tb = lane * NCLS;
    int nk = (q == 0) ? 21 : 20;                     // q==0 also owns c=80
    float x[21];
    #pragma unroll
    for (int k = 0; k < 21; ++k) {
        int c = q + 4 * k;
        x[k] = (k < nk) ? lx[tb + c] : -3.4e38f;
    }
    float pm = -3.4e38f;
    #pragma unroll
    for (int k = 0; k < 21; ++k) if (k < nk) pm = fmaxf(pm, x[k]);
    pmx[q * 64 + lane] = pm;
    __syncthreads();                                 // #2: partial max
    float m = fmaxf(fmaxf(pmx[lane], pmx[64 + lane]),
                    fmaxf(pmx[128 + lane], pmx[192 + lane]));

    float ps = 0.f;
    #pragma unroll
    for (int k = 0; k < 21; ++k) {
        if (k < nk) { x[k] = expf(x[k] - m); ps += x[k]; }
    }
    psm[q * 64 + lane] = ps;
    __syncthreads();                                 // #3: partial sum
    float s = (psm[lane] + psm[64 + lane]) + (psm[128 + lane] + psm[192 + lane]);

    float hi = 0.05000075f * s;
    float lo = 0.04999925f * s;
    u32 pass = 0, band = 0;
    u32 sizeok = sok[lane];
    if (active && sizeok) {
        #pragma unroll
        for (int k = 0; k < 21; ++k) {
            int c = q + 4 * k;
            if (k < nk && c >= 1) {
                bool pa = x[k] > hi;
                bool bd = (!pa) && (x[k] > lo);
                pass |= ((u32)pa) << k;
                band |= ((u32)bd) << k;
            }
        }
    }
    while (band) {
        int k = __builtin_ctz(band); band &= band - 1;
        int c = q + 4 * k;
        float e = expf(lx[tb + c] - m);
        if (e / s > 0.05f) pass |= 1u << k;
    }
    int cnt_t = __popc(pass);

    int pre = cnt_t;
    #pragma unroll
    for (int d = 1; d < 64; d <<= 1) {
        int o = __shfl_up(pre, d);
        if (lane >= d) pre += o;
    }
    if (lane == 63) wtt[q] = (u32)pre;
    __syncthreads();                                 // #4: wave totals
    u32 before = 0;
    for (int w = 0; w < 4; ++w) if (w < q) before += wtt[w];
    if (t == 0) {
        u32 tot = wtt[0] + wtt[1] + wtt[2] + wtt[3];
        sbase = tot ? atomicAdd(cnt + b * CNT_STRIDE, tot) : 0u;
    }
    __syncthreads();                                 // #5: block base
    u32 pos = sbase + before + (u32)(pre - cnt_t);

    u64* cb = cand + (size_t)b * cap;
    u32 flatneg = 0xFFFFFFFFu - (u32)p * NFG;
    while (pass) {
        int k = __builtin_ctz(pass); pass &= pass - 1;
        int c = q + 4 * k;
        float e = expf(lx[tb + c] - m);
        float d = e / s;
        if ((int)pos < cap) {
            u32 sb = __float_as_uint(d);
            cb[pos] = ((u64)sb << 32) | (u64)(flatneg - (u32)(c - 1));
            u32 bin = (sb - BASEBITS) >> 16; if (bin > NB - 1) bin = NB - 1;
            atomicAdd(&lhist[bin], 1u);              // LDS, ~14 adds per block
        }
        ++pos;
    }
    __syncthreads();                                 // #6: lhist complete
    u32* gh = ghist + b * NB;
    for (int i = t; i < NB; i += 256) {
        u32 v = lhist[i];
        if (v) atomicAdd(gh + i, v);                 // ~14 nonzero bins/block
    }
}

// ============================================================ suffix_find
// (rare fine-fallback path only): 8192-bin hierarchical suffix scan.
__device__ __forceinline__ void suffix_find(
    u32* hist, u32* wt, u32 K, int tid,
    volatile int* outI, volatile u32* outNext)
{
    int lane = tid & 63, w = tid >> 6;
    u32 v[8]; u32 tot = 0;
    #pragma unroll
    for (int k = 0; k < 8; ++k) { v[k] = hist[tid * 8 + k]; tot += v[k]; }
    u32 ws = tot;
    #pragma unroll
    for (int d = 1; d < 64; d <<= 1) {
        u32 o = __shfl_down(ws, d);
        if (lane + d < 64) ws += o;
    }
    if (lane == 0) wt[w] = ws;
    __syncthreads();
    u32 tail = 0;
    for (int w2 = w + 1; w2 < 16; ++w2) tail += wt[w2];
    u32 after = (ws - tot) + tail;
    u32 sufk[9];
    sufk[8] = after;
    #pragma unroll
    for (int k = 7; k >= 0; --k) sufk[k] = v[k] + sufk[k + 1];
    #pragma unroll
    for (int k = 0; k < 8; ++k) {
        if (sufk[k] >= K && sufk[k + 1] < K) {
            *outI = tid * 8 + k;
            *outNext = sufk[k + 1];
        }
    }
    __syncthreads();
}

// ============================================================ kernel 2
// FUSED select, ONE candidate pass (R11): threshold comes from the hist
// prebuilt in k_decode -- no hist pass here (R10's regression: each extra
// pass over the 250KB/image buffer costs ~5-8us of chained L2 latency on a
// 16-block kernel). Then compact -> hybrid bitonic sort -> prep.
__global__ __launch_bounds__(1024) void k_select(
    const u64* __restrict__ cand, const u32* __restrict__ cnt,
    const u32* __restrict__ ghist, const float* __restrict__ boxes,
    float* __restrict__ cscore, int* __restrict__ clabel,
    float4* __restrict__ cbox, float4* __restrict__ coffs,
    float* __restrict__ carea, u64* __restrict__ validw, int cap)
{
#pragma clang fp contract(off)
    __shared__ u32 h[NB];
    __shared__ u32 fh[8192];        // rare fine fallback only
    __shared__ u32 wt[16];
    __shared__ u64 buf[2048];
    __shared__ float red16[16];
    __shared__ int sh_c, sh_i2;
    __shared__ u32 sh_S, sh_next, sh_d, sh_m;
    int b = blockIdx.x, t = threadIdx.x, lane = t & 63;
    u32 n = min(cnt[b * CNT_STRIDE], (u32)cap);
    const u64* cb = cand + (size_t)b * cap;

    for (int i = t; i < NB; i += 1024) h[i] = ghist[b * NB + i];
    if (t == 0) { sh_c = -2; sh_i2 = -2; sh_S = 0; sh_next = 0; sh_m = 0; }
    __syncthreads();
    // ---- wave-0 suffix scan of 640 bins (10/lane) ----
    if (t < 64) {
        u32 v[10]; u32 tot = 0;
        #pragma unroll
        for (int k = 0; k < 10; ++k) { v[k] = h[t * 10 + k]; tot += v[k]; }
        u32 ws = tot;
        #pragma unroll
        for (int d = 1; d < 64; d <<= 1) {
            u32 o = (u32)__shfl_down((int)ws, d);
            if (t + d < 64) ws += o;
        }
        u32 suf[11];
        suf[10] = ws - tot;                          // suffix after my bins
        #pragma unroll
        for (int k = 9; k >= 0; --k) suf[k] = v[k] + suf[k + 1];
        #pragma unroll
        for (int k = 0; k < 10; ++k) {
            if (suf[k] >= (u32)KTOP && suf[k + 1] < (u32)KTOP) {
                sh_c = t * 10 + k; sh_S = suf[k]; sh_next = suf[k + 1];
            }
        }
    }
    __syncthreads();
    int c = sh_c;
    u32 T = 0;
    if (c >= 0) {
        u32 Tc = BASEBITS + ((u32)c << 16);
        if (sh_S <= 2048u) {
            T = Tc;                                  // common path, no pass
        } else {                                     // rare: gran-8 refine (1 pass)
            u32 nhi = sh_next;
            for (int i = t; i < 8192; i += 1024) fh[i] = 0;
            __syncthreads();
            for (u32 i = (u32)t; i < n; i += 1024) {
                u32 sb = (u32)(cb[i] >> 32);
                if ((sb & 0xFFFF0000u) == Tc)
                    atomicAdd(&fh[(sb >> 3) & 0x1FFFu], 1u);
            }
            __syncthreads();
            suffix_find(fh, wt, (u32)KTOP - nhi, t, &sh_i2, &sh_d);
            T = (sh_i2 >= 0) ? (Tc + ((u32)sh_i2 << 3)) : Tc;
        }
    }
    // ---- the ONE candidate pass: compact survivors (>= T) into LDS buf ----
    for (u32 bs0 = 0; bs0 < n; bs0 += 4096) {
        u32 i0 = bs0 + (u32)t;
        u64 k0 = 0, k1 = 0, k2 = 0, k3 = 0;
        bool q0 = i0 < n, q1 = i0 + 1024 < n, q2 = i0 + 2048 < n, q3 = i0 + 3072 < n;
        if (q0) k0 = cb[i0];
        if (q1) k1 = cb[i0 + 1024];
        if (q2) k2 = cb[i0 + 2048];
        if (q3) k3 = cb[i0 + 3072];
        #pragma unroll
        for (int e = 0; e < 4; ++e) {
            u64 key = (e == 0) ? k0 : (e == 1) ? k1 : (e == 2) ? k2 : k3;
            bool pr = (e == 0) ? q0 : (e == 1) ? q1 : (e == 2) ? q2 : q3;
            bool pick = pr && ((u32)(key >> 32) >= T);
            u64 bal = __ballot(pick);
            u32 wb = 0;
            if (lane == 0 && bal) wb = atomicAdd(&sh_m, (u32)__popcll(bal));
            wb = (u32)__shfl((int)wb, 0);
            if (pick) {
                u32 pos = wb + (u32)__popcll(bal & ((1ULL << lane) - 1ULL));
                if (pos < 2048) buf[pos] = key;
            }
        }
    }
    __syncthreads();
    u32 m = min(sh_m, 2048u);
    for (int i = t; i < 2048; i += 1024) if ((u32)i >= m) buf[i] = 0ULL;
    __syncthreads();
    // ---- hybrid bitonic sort, 2048 elems, full-key desc ----
    // j>=64 via LDS+barrier; j<=32 in-register via shfl_xor (same wave).
    for (int k = 2; k <= 2048; k <<= 1) {
        for (int j = k >> 1; j >= 64; j >>= 1) {
            #pragma unroll
            for (int e = 0; e < 2; ++e) {
                int i = t + e * 1024;
                int ixj = i ^ j;
                if (ixj > i) {
                    u64 a = buf[i], bb = buf[ixj];
                    bool up = (i & k) == 0;
                    if (up ? (a < bb) : (a > bb)) { buf[i] = bb; buf[ixj] = a; }
                }
            }
            __syncthreads();
        }
        u64 v0 = buf[t], v1 = buf[t + 1024];
        bool up0 = (t & k) == 0;
        bool up1 = ((t + 1024) & k) == 0;
        int js = ((k >> 1) < 32) ? (k >> 1) : 32;
        for (int j = js; j >= 1; j >>= 1) {
            u64 o0 = __shfl_xor(v0, j);
            u64 o1 = __shfl_xor(v1, j);
            bool lo0 = (t & j) == 0;
            v0 = (lo0 == up0) ? (v0 > o0 ? v0 : o0) : (v0 < o0 ? v0 : o0);
            v1 = (lo0 == up1) ? (v1 > o1 ? v1 : o1) : (v1 < o1 ? v1 : o1);
        }
        buf[t] = v0; buf[t + 1024] = v1;
        __syncthreads();
    }
    // ---- fused prep: t owns slot t of KPAD ----
    u64 key = (t < KTOP) ? buf[t] : 0ULL;
    float s = __uint_as_float((u32)(key >> 32));
    bool valid = s > 0.0f;
    u32 flat = valid ? (0xFFFFFFFFu - (u32)key) : 0u;
    int prior = (int)(flat / NFG);
    int cls = (int)(flat - (u32)prior * NFG) + 1;
    float4 bx = make_float4(0.f, 0.f, 0.f, 0.f);
    if (valid) bx = ((const float4*)boxes)[b * NP + prior];
    cscore[b * KPAD + t] = s;
    clabel[b * KPAD + t] = cls;
    cbox[b * KPAD + t] = bx;
    u64 vb = __ballot(valid);
    if (lane == 0) validw[b * 16 + (t >> 6)] = vb;
    float lm = valid ? fmaxf(fmaxf(bx.x, bx.y), fmaxf(bx.z, bx.w)) : 0.0f;
    lm = fmaxf(lm, 0.0f);
    #pragma unroll
    for (int d = 1; d < 64; d <<= 1) lm = fmaxf(lm, __shfl_xor(lm, d));
    if (lane == 0) red16[t >> 6] = lm;
    __syncthreads();
    float mc = red16[0];
    #pragma unroll
    for (int w = 1; w < 16; ++w) mc = fmaxf(mc, red16[w]);
    float off = (float)cls * (mc + 1.0f);
    float4 ob = valid ? make_float4(bx.x + off, bx.y + off, bx.z + off, bx.w + off)
                      : make_float4(0.f, 0.f, 0.f, 0.f);
    float area = valid ? (ob.z - ob.x) * (ob.w - ob.y) : 0.0f;
    coffs[b * KPAD + t] = ob;
    carea[b * KPAD + t] = area;
}

// ============================================================ kernel 3
// suppression bitmask, COLUMN-major: cmask[b][w][j] bit k = row (64w+k)
// suppresses column j. 256 blocks (keeps iou work spread across CUs).
__global__ __launch_bounds__(1024) void k_iou(
    const float4* __restrict__ coffs, const float* __restrict__ carea,
    u64* __restrict__ cmask)
{
#pragma clang fp contract(off)
    __shared__ float4 bs[KPAD];
    __shared__ float as_[KPAD];
    int b = blockIdx.x >> 4, tile = blockIdx.x & 15;
    int t = threadIdx.x;
    bs[t] = coffs[b * KPAD + t];
    as_[t] = carea[b * KPAD + t];
    __syncthreads();
    int j = tile * 64 + (t & 63);                  // column (suppressee)
    int w = t >> 6;                                // row word
    float4 bj = bs[j];
    float aj = as_[j];
    int r0 = w * 64;
    u64 bits = 0;
    #pragma unroll 4
    for (int k = 0; k < 64; ++k) {
        int r = r0 + k;                            // wave-uniform row
        float4 br = bs[r];
        float ar = as_[r];
        float ltx = fmaxf(br.x, bj.x), lty = fmaxf(br.y, bj.y);
        float rbx = fminf(br.z, bj.z), rby = fminf(br.w, bj.w);
        float wx = fmaxf(rbx - ltx, 0.0f), wy = fmaxf(rby - lty, 0.0f);
        float inter = wx * wy;
        float denom = ((ar + aj) - inter) + 1e-9f;
        float iou = inter / denom;
        bool sup = (iou > 0.45f) && (j > r);
        bits |= ((u64)sup) << k;
    }
    cmask[((size_t)b * 16 + w) * KPAD + j] = bits;
}

// ============================================================ kernel 4
// NMS via ballot fixpoint (greedy kept-set = unique fixpoint; typ. <5 iters).
__global__ __launch_bounds__(64) void k_nms(
    const u64* __restrict__ cmask, const u64* __restrict__ validw,
    const float* __restrict__ cscore, const int* __restrict__ clabel,
    const float4* __restrict__ cbox, float* __restrict__ out)
{
    int b = blockIdx.x, lane = threadIdx.x;
    const u64* cm = cmask + (size_t)b * 16 * KPAD;
    u64 kept[16];
    u64 cw[16];
    #pragma unroll
    for (int w = 0; w < 16; ++w) cw[w] = cm[w * KPAD + lane];   // group 0 cols
    #pragma unroll
    for (int g = 0; g < 16; ++g) {
        u64 vg = validw[b * 16 + g];
        bool rem = false;
        #pragma unroll
        for (int w = 0; w < 16; ++w)
            if (w < g) rem |= (kept[w] & cw[w]) != 0ULL;
        u64 cg = cw[g];
        bool myv = ((vg >> lane) & 1ULL) && !rem;
        if (g < 15) {                               // prefetch next group's cols
            int cbase = (g + 1) * 64 + lane;
            #pragma unroll
            for (int w = 0; w < 16; ++w) cw[w] = cm[w * KPAD + cbase];
        }
        u64 K = __ballot(myv);
        for (;;) {
            u64 K2 = __ballot(myv && ((K & cg) == 0ULL));
            if (K2 == K) break;
            K = K2;
        }
        kept[g] = K;                                // wave-uniform
    }
    __shared__ u64 sk[16];
    __shared__ int pfx[17];
    __shared__ int slot[DETS];
    if (lane == 0) {
        #pragma unroll
        for (int w = 0; w < 16; ++w) sk[w] = kept[w];
        int run = 0;
        #pragma unroll
        for (int l = 0; l < 16; ++l) { pfx[l] = run; run += __popcll(kept[l]); }
        pfx[16] = run;
    }
    __syncthreads();
    if (lane < 16) {
        int r = pfx[lane];
        u64 wv = sk[lane];
        while (wv && r < DETS) {
            int bit = __builtin_ctzll(wv);
            slot[r] = lane * 64 + bit;
            ++r;
            wv &= wv - 1;
        }
    }
    __syncthreads();
    int total = min(pfx[16], DETS);
    for (int r = lane; r < DETS; r += 64) {
        float4 bx = make_float4(0.f, 0.f, 0.f, 0.f);
        float s = 0.0f;
        int lb = -1;
        if (r < total) {
            int cdx = slot[r];
            bx = cbox[b * KPAD + cdx];
            s = cscore[b * KPAD + cdx];
            lb = clabel[b * KPAD + cdx];
        }
        float* ob = out + ((size_t)b * DETS + r) * 4;
        ob[0] = bx.x; ob[1] = bx.y; ob[2] = bx.z; ob[3] = bx.w;
        out[NIMG * DETS * 4 + b * DETS + r] = s;
        out[NIMG * DETS * 4 + NIMG * DETS + b * DETS + r] = (float)lb;
    }
}

// ============================================================ launch
extern "C" void kernel_launch(void* const* d_in, const int* in_sizes, int n_in,
                              void* d_out, int out_size, void* d_ws, size_t ws_size,
                              hipStream_t stream) {
    const float* logits = (const float*)d_in[0];
    const float* rel    = (const float*)d_in[1];
    const float* priors = (const float*)d_in[2];
    const int*   tsz    = (const int*)d_in[3];
    float* out = (float*)d_out;
    char* ws = (char*)d_ws;

    float* boxes  = (float*)(ws + OFF_BOXES);
    u32*   cnt    = (u32*)(ws + OFF_CNT);
    u32*   ghist  = (u32*)(ws + OFF_GHIST);
    float* cscore = (float*)(ws + OFF_CSCORE);
    int*   clabel = (int*)(ws + OFF_CLABEL);
    float4* cbox  = (float4*)(ws + OFF_CBOX);
    float4* coffs = (float4*)(ws + OFF_COFFS);
    float* carea  = (float*)(ws + OFF_CAREA);
    u64*   validw = (u64*)(ws + OFF_VALIDW);
    u64*   cmask  = (u64*)(ws + OFF_MASK);
    u64*   cand   = (u64*)(ws + OFF_CAND);

    long long avail = ((long long)ws_size - (long long)OFF_CAND) / (NIMG * 8);
    int cap = (int)(avail < CAPMAX ? (avail > 0 ? avail : 1) : CAPMAX);
    cap &= ~1;                                    // even -> 16B-aligned per-image base

    hipMemsetAsync(cnt, 0, MEMSET_LEN, stream);   // cnt + ghist
    k_decode<<<NIMG * TILEB, 256, 0, stream>>>(logits, rel, priors, tsz,
                                               boxes, cand, cnt, ghist, cap);
    k_select<<<NIMG, 1024, 0, stream>>>(cand, cnt, ghist, boxes, cscore, clabel,
                                        cbox, coffs, carea, validw, cap);
    k_iou<<<NIMG * 16, 1024, 0, stream>>>(coffs, carea, cmask);
    k_nms<<<NIMG, 64, 0, stream>>>(cmask, validw, cscore, clabel, cbox, out);
}